// Round 5
// baseline (182.655 us; speedup 1.0000x reference)
//
#include <hip/hip_runtime.h>
#include <hip/hip_bf16.h>
#include <stdint.h>

#define Bn 8
#define Sn 2048
#define Hn 768
#define Rn 768
#define Mn (Bn*Sn)          // 16384

typedef __attribute__((ext_vector_type(8))) __bf16 bf16x8;
typedef __attribute__((ext_vector_type(4))) float f32x4;

__device__ __forceinline__ void gload_lds16(const void* g, void* l) {
    __builtin_amdgcn_global_load_lds(
        (const __attribute__((address_space(1))) uint32_t*)g,
        (__attribute__((address_space(3))) uint32_t*)l,
        16, 0, 0);
}

__device__ __forceinline__ unsigned short f2bf_bits(float f) {
    uint32_t u = __builtin_bit_cast(uint32_t, f);
    u += 0x7fffu + ((u >> 16) & 1u);
    return (unsigned short)(u >> 16);
}

// ---------------- convert + transpose proj: projT[r][h] = bf16(proj[h][r]) ----------------
__global__ void cvt_projT(const float* __restrict__ proj, __hip_bfloat16* __restrict__ projT) {
    int t = blockIdx.x * blockDim.x + threadIdx.x;
    if (t < Hn * Rn) {
        int r = t / Hn;
        int h = t - r * Hn;
        projT[t] = __hip_bfloat16(__builtin_bit_cast(__hip_bfloat16_raw, f2bf_bits(proj[h * Rn + r])));
    }
}

// ---------------- fused projection GEMM ----------------
// Grid: 768 linear blocks, XCD-grouped so the 6 col-tiles of one 128-row A strip
// run on the same XCD (A strip 393 KB f32 -> L2-resident; 5 of 6 re-reads are L2 hits).
#define BKP 32
__global__ __launch_bounds__(256, 3)
void gemm_proj_fused(const float* __restrict__ A,            // [Mn][Hn] f32
                     const __hip_bfloat16* __restrict__ Bt,  // [Rn][Hn] bf16
                     __hip_bfloat16* __restrict__ Ct,        // [Mn][Rn] bf16
                     float* __restrict__ sqv) {              // [Mn] f32, pre-zeroed
    __shared__ float Af[128 * BKP];             // 16 KB
    __shared__ __hip_bfloat16 Bs[128 * BKP];    //  8 KB
    const int tid  = threadIdx.x;
    const int lane = tid & 63;
    const int w    = tid >> 6;
    const int wr   = w >> 1, wc = w & 1;

    const int L   = blockIdx.x;        // 0..767
    const int xcd = L & 7;
    const int q   = L >> 3;            // 0..95
    const int row0 = (xcd * 16 + q / 6) * 128;
    const int col0 = (q % 6) * 128;

    f32x4 acc[4][4];
#pragma unroll
    for (int i = 0; i < 4; ++i)
#pragma unroll
        for (int j = 0; j < 4; ++j) acc[i][j] = (f32x4){0.f, 0.f, 0.f, 0.f};

    const int cl = lane >> 4;     // 0..3: 8-float (two 16B chunks) k-group
    const int rA = lane & 15;

    for (int k0 = 0; k0 < Hn; k0 += BKP) {
        // A: 128 rows x 8 chunks (16B=4 f32) = 1024 chunks, 4/thread; XOR r&7 swizzle
#pragma unroll
        for (int i = 0; i < 4; ++i) {
            int cid = tid + i * 256;
            int r = cid >> 3;
            int c = cid & 7;
            int csrc = c ^ (r & 7);
            gload_lds16(A + (size_t)(row0 + r) * Hn + k0 + csrc * 4, Af + cid * 4);
        }
        // B: 128 rows x 4 chunks (16B=8 bf16) = 512 chunks, 2/thread; XOR (r>>1)&3
#pragma unroll
        for (int i = 0; i < 2; ++i) {
            int c16 = tid + i * 256;
            int r = c16 >> 2;
            int c = c16 & 3;
            int csrc = c ^ ((r >> 1) & 3);
            gload_lds16(Bt + (size_t)(col0 + r) * Hn + k0 + csrc * 8, Bs + c16 * 8);
        }
        __syncthreads();

        bf16x8 af[4], bfr[4];
#pragma unroll
        for (int f = 0; f < 4; ++f) {
            int ra = wr * 64 + f * 16 + rA;
            int rb = wc * 64 + f * 16 + rA;
            f32x4 a0 = *(const f32x4*)(Af + ra * BKP + (((2 * cl + 0) ^ (ra & 7)) * 4));
            f32x4 a1 = *(const f32x4*)(Af + ra * BKP + (((2 * cl + 1) ^ (ra & 7)) * 4));
            union { bf16x8 v; __bf16 e[8]; } u;
#pragma unroll
            for (int p = 0; p < 4; ++p) { u.e[p] = (__bf16)a0[p]; u.e[4 + p] = (__bf16)a1[p]; }
            af[f]  = u.v;
            bfr[f] = *(const bf16x8*)(Bs + rb * BKP + (cl ^ ((rb >> 1) & 3)) * 8);
        }
#pragma unroll
        for (int fm = 0; fm < 4; ++fm)
#pragma unroll
            for (int fn = 0; fn < 4; ++fn)
                acc[fm][fn] = __builtin_amdgcn_mfma_f32_16x16x32_bf16(af[fm], bfr[fn], acc[fm][fn], 0, 0, 0);
        __syncthreads();
    }

    // epilogue: store bf16 t, accumulate row sums of rounded t^2
    const int cr = (lane >> 4) * 4;
    const int cc = lane & 15;
    float rowsum[4][4];
#pragma unroll
    for (int fm = 0; fm < 4; ++fm)
#pragma unroll
        for (int j = 0; j < 4; ++j) rowsum[fm][j] = 0.f;

#pragma unroll
    for (int fm = 0; fm < 4; ++fm)
#pragma unroll
        for (int fn = 0; fn < 4; ++fn)
#pragma unroll
            for (int j = 0; j < 4; ++j) {
                int row = row0 + wr * 64 + fm * 16 + cr + j;
                int col = col0 + wc * 64 + fn * 16 + cc;
                unsigned short bits = f2bf_bits(acc[fm][fn][j]);
                Ct[(size_t)row * Rn + col] =
                    __hip_bfloat16(__builtin_bit_cast(__hip_bfloat16_raw, bits));
                float vr = __builtin_bit_cast(float, (uint32_t)bits << 16);
                rowsum[fm][j] = fmaf(vr, vr, rowsum[fm][j]);
            }

#pragma unroll
    for (int fm = 0; fm < 4; ++fm)
#pragma unroll
        for (int j = 0; j < 4; ++j) {
            float s = rowsum[fm][j];
            s += __shfl_xor(s, 1, 64);
            s += __shfl_xor(s, 2, 64);
            s += __shfl_xor(s, 4, 64);
            s += __shfl_xor(s, 8, 64);
            if (cc == 0)
                atomicAdd(&sqv[row0 + wr * 64 + fm * 16 + cr + j], s);
        }
}

// ---------------- symmetric gram, BK=64 + LDS XOR swizzle ----------------
// LDS trimmed to 32 KB (transpose scratch aliases As, which is dead after the
// K-loop's final barrier) -> 5 blocks/CU -> all 1088 blocks co-resident (no tail).
#define BKG 64
__global__ __launch_bounds__(256, 5)
void gram_sym(const __hip_bfloat16* __restrict__ T, const float* __restrict__ sq,
              float* __restrict__ out) {
    __shared__ __hip_bfloat16 As[128 * BKG];   // 16 KB
    __shared__ __hip_bfloat16 Bs[128 * BKG];   // 16 KB

    const int tid  = threadIdx.x;
    const int lane = tid & 63;
    const int w    = tid >> 6;
    const int wr   = w >> 1, wc = w & 1;

    const int L = blockIdx.x;
    const int b = L & 7;
    int tile_id = L >> 3;               // 0..135
    int ty = 0;
    {
        int rowlen = 16;
        while (tile_id >= rowlen) { tile_id -= rowlen; --rowlen; ++ty; }
    }
    const int tx = ty + tile_id;
    const bool diag = (ty == tx);
    const int row0 = ty * 128;
    const int col0 = tx * 128;

    const __hip_bfloat16* Tb = T + (size_t)b * Sn * Rn;
    const float* sqb = sq + b * Sn;
    float* outb = out + (size_t)b * Sn * Sn;

    f32x4 acc[4][4];
#pragma unroll
    for (int i = 0; i < 4; ++i)
#pragma unroll
        for (int j = 0; j < 4; ++j) acc[i][j] = (f32x4){0.f, 0.f, 0.f, 0.f};

    const int cl = lane >> 4;
    const int rA = lane & 15;

    for (int k0 = 0; k0 < Rn; k0 += BKG) {
#pragma unroll
        for (int i = 0; i < 4; ++i) {
            int cid = tid + i * 256;
            int r = cid >> 3;
            int c = cid & 7;
            int csrc = c ^ (r & 7);
            gload_lds16(Tb + (size_t)(row0 + r) * Rn + k0 + csrc * 8, As + cid * 8);
            if (!diag)
                gload_lds16(Tb + (size_t)(col0 + r) * Rn + k0 + csrc * 8, Bs + cid * 8);
        }
        __syncthreads();

        const __hip_bfloat16* Bsrc = diag ? As : Bs;
#pragma unroll
        for (int ks = 0; ks < 2; ++ks) {
            const int clk = cl + ks * 4;
            bf16x8 af[4], bfr[4];
#pragma unroll
            for (int f = 0; f < 4; ++f) {
                int ra = wr * 64 + f * 16 + rA;
                int rb = wc * 64 + f * 16 + rA;
                af[f]  = *(const bf16x8*)(As   + ra * BKG + (clk ^ (ra & 7)) * 8);
                bfr[f] = *(const bf16x8*)(Bsrc + rb * BKG + (clk ^ (rb & 7)) * 8);
            }
#pragma unroll
            for (int fm = 0; fm < 4; ++fm)
#pragma unroll
                for (int fn = 0; fn < 4; ++fn)
                    acc[fm][fn] = __builtin_amdgcn_mfma_f32_16x16x32_bf16(af[fm], bfr[fn], acc[fm][fn], 0, 0, 0);
        }
        __syncthreads();
    }

    // epilogue (strictly after final barrier: As is dead, reuse as transpose scratch)
    const int cr = (lane >> 4) * 4;
    const int cc = lane & 15;
    float* sc = (float*)As + w * (16 * 20);

    float sqr[4][4];
#pragma unroll
    for (int fm = 0; fm < 4; ++fm)
#pragma unroll
        for (int j = 0; j < 4; ++j)
            sqr[fm][j] = sqb[row0 + wr * 64 + fm * 16 + cr + j];

#pragma unroll
    for (int fm = 0; fm < 4; ++fm)
#pragma unroll
        for (int fn = 0; fn < 4; ++fn) {
            const int col = col0 + wc * 64 + fn * 16 + cc;
            const float sqc = sqb[col];
            float v[4];
#pragma unroll
            for (int j = 0; j < 4; ++j) {
                const int row = row0 + wr * 64 + fm * 16 + cr + j;
                v[j] = fmaxf(sqr[fm][j] + sqc - 2.0f * acc[fm][fn][j], 0.0f);
                outb[(size_t)row * Sn + col] = v[j];
            }
            if (!diag) {
#pragma unroll
                for (int j = 0; j < 4; ++j) sc[(cr + j) * 20 + cc] = v[j];
                float4 tv = *(const float4*)(sc + cc * 20 + cr);
#pragma unroll
                for (int j = 0; j < 4; ++j) {
                    const int mrow = col0 + wc * 64 + fn * 16 + cr + j;
                    const int mcol = row0 + wr * 64 + fm * 16 + cc;
                    outb[(size_t)mrow * Sn + mcol] = ((const float*)&tv)[j];
                }
            }
        }
}

extern "C" void kernel_launch(void* const* d_in, const int* in_sizes, int n_in,
                              void* d_out, int out_size, void* d_ws, size_t ws_size,
                              hipStream_t stream) {
    const float* batch = (const float*)d_in[0];   // [8][2048][768] f32
    const float* proj  = (const float*)d_in[1];   // [768][768] f32
    float* out = (float*)d_out;                   // [8][2048][2048] f32

    char* ws = (char*)d_ws;
    __hip_bfloat16* projT = (__hip_bfloat16*)(ws);                 //  1,179,648 B
    __hip_bfloat16* t_bf  = (__hip_bfloat16*)(ws + 1179648);       // 25,165,824 B
    float*          sqv   = (float*)(ws + 1179648 + 25165824);     //     65,536 B

    hipMemsetAsync(sqv, 0, Mn * sizeof(float), stream);
    cvt_projT<<<(Hn * Rn + 255) / 256, 256, 0, stream>>>(proj, projT);
    gemm_proj_fused<<<768, 256, 0, stream>>>(batch, projT, t_bf, sqv);
    gram_sym<<<8 * 136, 256, 0, stream>>>(t_bf, sqv, out);
}

// Round 6
// 100.040 us; speedup vs baseline: 1.8258x; 1.8258x over previous
//
#include <hip/hip_runtime.h>
#include <hip/hip_bf16.h>
#include <stdint.h>

#define Bn 8
#define Sn 2048
#define Hn 768
#define Rn 768
#define Mn (Bn*Sn)          // 16384

typedef __attribute__((ext_vector_type(8))) __bf16 bf16x8;
typedef __attribute__((ext_vector_type(4))) float f32x4;

__device__ __forceinline__ void gload_lds16(const void* g, void* l) {
    __builtin_amdgcn_global_load_lds(
        (const __attribute__((address_space(1))) uint32_t*)g,
        (__attribute__((address_space(3))) uint32_t*)l,
        16, 0, 0);
}

__device__ __forceinline__ unsigned short f2bf_bits(float f) {
    uint32_t u = __builtin_bit_cast(uint32_t, f);
    u += 0x7fffu + ((u >> 16) & 1u);
    return (unsigned short)(u >> 16);
}

// ---------------- convert + transpose proj: projT[r][h] = bf16(proj[h][r]) ----------------
__global__ void cvt_projT(const float* __restrict__ proj, __hip_bfloat16* __restrict__ projT) {
    int t = blockIdx.x * blockDim.x + threadIdx.x;
    if (t < Hn * Rn) {
        int r = t / Hn;
        int h = t - r * Hn;
        projT[t] = __hip_bfloat16(__builtin_bit_cast(__hip_bfloat16_raw, f2bf_bits(proj[h * Rn + r])));
    }
}

// ---------------- fused projection GEMM ----------------
// Grid: 768 linear blocks, XCD-grouped so the 6 col-tiles of one 128-row A strip
// run on the same XCD (A strip 393 KB f32 -> L2-resident; 5 of 6 re-reads are L2 hits).
#define BKP 32
__global__ __launch_bounds__(256, 3)
void gemm_proj_fused(const float* __restrict__ A,            // [Mn][Hn] f32
                     const __hip_bfloat16* __restrict__ Bt,  // [Rn][Hn] bf16
                     __hip_bfloat16* __restrict__ Ct,        // [Mn][Rn] bf16
                     float* __restrict__ sqv) {              // [Mn] f32, pre-zeroed
    __shared__ float Af[128 * BKP];             // 16 KB
    __shared__ __hip_bfloat16 Bs[128 * BKP];    //  8 KB
    const int tid  = threadIdx.x;
    const int lane = tid & 63;
    const int w    = tid >> 6;
    const int wr   = w >> 1, wc = w & 1;

    const int L   = blockIdx.x;        // 0..767
    const int xcd = L & 7;
    const int q   = L >> 3;            // 0..95
    const int row0 = (xcd * 16 + q / 6) * 128;
    const int col0 = (q % 6) * 128;

    f32x4 acc[4][4];
#pragma unroll
    for (int i = 0; i < 4; ++i)
#pragma unroll
        for (int j = 0; j < 4; ++j) acc[i][j] = (f32x4){0.f, 0.f, 0.f, 0.f};

    const int cl = lane >> 4;     // 0..3: 8-float (two 16B chunks) k-group
    const int rA = lane & 15;

    for (int k0 = 0; k0 < Hn; k0 += BKP) {
        // A: 128 rows x 8 chunks (16B=4 f32) = 1024 chunks, 4/thread; XOR r&7 swizzle
#pragma unroll
        for (int i = 0; i < 4; ++i) {
            int cid = tid + i * 256;
            int r = cid >> 3;
            int c = cid & 7;
            int csrc = c ^ (r & 7);
            gload_lds16(A + (size_t)(row0 + r) * Hn + k0 + csrc * 4, Af + cid * 4);
        }
        // B: 128 rows x 4 chunks (16B=8 bf16) = 512 chunks, 2/thread; XOR (r>>1)&3
#pragma unroll
        for (int i = 0; i < 2; ++i) {
            int c16 = tid + i * 256;
            int r = c16 >> 2;
            int c = c16 & 3;
            int csrc = c ^ ((r >> 1) & 3);
            gload_lds16(Bt + (size_t)(col0 + r) * Hn + k0 + csrc * 8, Bs + c16 * 8);
        }
        __syncthreads();

        bf16x8 af[4], bfr[4];
#pragma unroll
        for (int f = 0; f < 4; ++f) {
            int ra = wr * 64 + f * 16 + rA;
            int rb = wc * 64 + f * 16 + rA;
            f32x4 a0 = *(const f32x4*)(Af + ra * BKP + (((2 * cl + 0) ^ (ra & 7)) * 4));
            f32x4 a1 = *(const f32x4*)(Af + ra * BKP + (((2 * cl + 1) ^ (ra & 7)) * 4));
            union { bf16x8 v; __bf16 e[8]; } u;
#pragma unroll
            for (int p = 0; p < 4; ++p) { u.e[p] = (__bf16)a0[p]; u.e[4 + p] = (__bf16)a1[p]; }
            af[f]  = u.v;
            bfr[f] = *(const bf16x8*)(Bs + rb * BKP + (cl ^ ((rb >> 1) & 3)) * 8);
        }
#pragma unroll
        for (int fm = 0; fm < 4; ++fm)
#pragma unroll
            for (int fn = 0; fn < 4; ++fn)
                acc[fm][fn] = __builtin_amdgcn_mfma_f32_16x16x32_bf16(af[fm], bfr[fn], acc[fm][fn], 0, 0, 0);
        __syncthreads();
    }

    // epilogue: store bf16 t, accumulate row sums of rounded t^2
    const int cr = (lane >> 4) * 4;
    const int cc = lane & 15;
    float rowsum[4][4];
#pragma unroll
    for (int fm = 0; fm < 4; ++fm)
#pragma unroll
        for (int j = 0; j < 4; ++j) rowsum[fm][j] = 0.f;

#pragma unroll
    for (int fm = 0; fm < 4; ++fm)
#pragma unroll
        for (int fn = 0; fn < 4; ++fn)
#pragma unroll
            for (int j = 0; j < 4; ++j) {
                int row = row0 + wr * 64 + fm * 16 + cr + j;
                int col = col0 + wc * 64 + fn * 16 + cc;
                unsigned short bits = f2bf_bits(acc[fm][fn][j]);
                Ct[(size_t)row * Rn + col] =
                    __hip_bfloat16(__builtin_bit_cast(__hip_bfloat16_raw, bits));
                float vr = __builtin_bit_cast(float, (uint32_t)bits << 16);
                rowsum[fm][j] = fmaf(vr, vr, rowsum[fm][j]);
            }

#pragma unroll
    for (int fm = 0; fm < 4; ++fm)
#pragma unroll
        for (int j = 0; j < 4; ++j) {
            float s = rowsum[fm][j];
            s += __shfl_xor(s, 1, 64);
            s += __shfl_xor(s, 2, 64);
            s += __shfl_xor(s, 4, 64);
            s += __shfl_xor(s, 8, 64);
            if (cc == 0)
                atomicAdd(&sqv[row0 + wr * 64 + fm * 16 + cr + j], s);
        }
}

// ---------------- symmetric gram, BK=64 + LDS XOR swizzle ----------------
// __launch_bounds__(256,4): reg budget 128 >= ~112 live (64 AGPR acc + addressing);
// (256,5) budget of ~102 forced K-loop accumulator spills to scratch (R5: +70MB
// FETCH, +140MB WRITE, 2.6x slower). 4 blocks/CU is reg-limited anyway.
#define BKG 64
__global__ __launch_bounds__(256, 4)
void gram_sym(const __hip_bfloat16* __restrict__ T, const float* __restrict__ sq,
              float* __restrict__ out) {
    __shared__ __hip_bfloat16 As[128 * BKG];   // 16 KB
    __shared__ __hip_bfloat16 Bs[128 * BKG];   // 16 KB

    const int tid  = threadIdx.x;
    const int lane = tid & 63;
    const int w    = tid >> 6;
    const int wr   = w >> 1, wc = w & 1;

    const int L = blockIdx.x;
    const int b = L & 7;
    int tile_id = L >> 3;               // 0..135
    int ty = 0;
    {
        int rowlen = 16;
        while (tile_id >= rowlen) { tile_id -= rowlen; --rowlen; ++ty; }
    }
    const int tx = ty + tile_id;
    const bool diag = (ty == tx);
    const int row0 = ty * 128;
    const int col0 = tx * 128;

    const __hip_bfloat16* Tb = T + (size_t)b * Sn * Rn;
    const float* sqb = sq + b * Sn;
    float* outb = out + (size_t)b * Sn * Sn;

    f32x4 acc[4][4];
#pragma unroll
    for (int i = 0; i < 4; ++i)
#pragma unroll
        for (int j = 0; j < 4; ++j) acc[i][j] = (f32x4){0.f, 0.f, 0.f, 0.f};

    const int cl = lane >> 4;
    const int rA = lane & 15;

    for (int k0 = 0; k0 < Rn; k0 += BKG) {
#pragma unroll
        for (int i = 0; i < 4; ++i) {
            int cid = tid + i * 256;
            int r = cid >> 3;
            int c = cid & 7;
            int csrc = c ^ (r & 7);
            gload_lds16(Tb + (size_t)(row0 + r) * Rn + k0 + csrc * 8, As + cid * 8);
            if (!diag)
                gload_lds16(Tb + (size_t)(col0 + r) * Rn + k0 + csrc * 8, Bs + cid * 8);
        }
        __syncthreads();

        const __hip_bfloat16* Bsrc = diag ? As : Bs;
#pragma unroll
        for (int ks = 0; ks < 2; ++ks) {
            const int clk = cl + ks * 4;
            bf16x8 af[4], bfr[4];
#pragma unroll
            for (int f = 0; f < 4; ++f) {
                int ra = wr * 64 + f * 16 + rA;
                int rb = wc * 64 + f * 16 + rA;
                af[f]  = *(const bf16x8*)(As   + ra * BKG + (clk ^ (ra & 7)) * 8);
                bfr[f] = *(const bf16x8*)(Bsrc + rb * BKG + (clk ^ (rb & 7)) * 8);
            }
#pragma unroll
            for (int fm = 0; fm < 4; ++fm)
#pragma unroll
                for (int fn = 0; fn < 4; ++fn)
                    acc[fm][fn] = __builtin_amdgcn_mfma_f32_16x16x32_bf16(af[fm], bfr[fn], acc[fm][fn], 0, 0, 0);
        }
        __syncthreads();
    }

    // epilogue (strictly after final barrier: As is dead, reuse as transpose scratch)
    const int cr = (lane >> 4) * 4;
    const int cc = lane & 15;
    float* sc = (float*)As + w * (16 * 20);

    float sqr[4][4];
#pragma unroll
    for (int fm = 0; fm < 4; ++fm)
#pragma unroll
        for (int j = 0; j < 4; ++j)
            sqr[fm][j] = sqb[row0 + wr * 64 + fm * 16 + cr + j];

#pragma unroll
    for (int fm = 0; fm < 4; ++fm)
#pragma unroll
        for (int fn = 0; fn < 4; ++fn) {
            const int col = col0 + wc * 64 + fn * 16 + cc;
            const float sqc = sqb[col];
            float v[4];
#pragma unroll
            for (int j = 0; j < 4; ++j) {
                const int row = row0 + wr * 64 + fm * 16 + cr + j;
                v[j] = fmaxf(sqr[fm][j] + sqc - 2.0f * acc[fm][fn][j], 0.0f);
                outb[(size_t)row * Sn + col] = v[j];
            }
            if (!diag) {
#pragma unroll
                for (int j = 0; j < 4; ++j) sc[(cr + j) * 20 + cc] = v[j];
                float4 tv = *(const float4*)(sc + cc * 20 + cr);
#pragma unroll
                for (int j = 0; j < 4; ++j) {
                    const int mrow = col0 + wc * 64 + fn * 16 + cr + j;
                    const int mcol = row0 + wr * 64 + fm * 16 + cc;
                    outb[(size_t)mrow * Sn + mcol] = ((const float*)&tv)[j];
                }
            }
        }
}

extern "C" void kernel_launch(void* const* d_in, const int* in_sizes, int n_in,
                              void* d_out, int out_size, void* d_ws, size_t ws_size,
                              hipStream_t stream) {
    const float* batch = (const float*)d_in[0];   // [8][2048][768] f32
    const float* proj  = (const float*)d_in[1];   // [768][768] f32
    float* out = (float*)d_out;                   // [8][2048][2048] f32

    char* ws = (char*)d_ws;
    __hip_bfloat16* projT = (__hip_bfloat16*)(ws);                 //  1,179,648 B
    __hip_bfloat16* t_bf  = (__hip_bfloat16*)(ws + 1179648);       // 25,165,824 B
    float*          sqv   = (float*)(ws + 1179648 + 25165824);     //     65,536 B

    hipMemsetAsync(sqv, 0, Mn * sizeof(float), stream);
    cvt_projT<<<(Hn * Rn + 255) / 256, 256, 0, stream>>>(proj, projT);
    gemm_proj_fused<<<768, 256, 0, stream>>>(batch, projT, t_bf, sqv);
    gram_sym<<<8 * 136, 256, 0, stream>>>(t_bf, sqv, out);
}